// Round 12
// baseline (104.353 us; speedup 1.0000x reference)
//
#include <hip/hip_runtime.h>
#include <math.h>

#define D 512
#define TEMP_INV 14.285714285714286f  // 1/0.07
#define NBT 64                         // 4096 / 64 tile grid dim
#define NTILE (NBT * (NBT + 1) / 2)    // 2080 upper-tri 64x64 tiles
#define NBLKS (NTILE / 4)              // 520 blocks, 4 waves (tiles) each

typedef int v8i __attribute__((ext_vector_type(8)));     // 32 fp8 elems
typedef float f32x16 __attribute__((ext_vector_type(16)));

// ws layout (float units):
//   [0]              neg_sum accumulator (float atomic)
//   [64 .. 64+2048)  p values (positive-pair logits)
//   [4096 .. )       efp8: normalized fp8(e4m3) matrix [4096][512] (2 MB)

// One wave per row: rsqrt(sum sq), scale, cvt to fp8 e4m3 (OCP), store packed.
__global__ void infonce_norm_cast_kernel(const float* __restrict__ emb,
                                         float* __restrict__ ws, int nrows) {
    if (blockIdx.x == 0 && threadIdx.x == 0) ws[0] = 0.0f;  // zero neg_sum
    unsigned int* __restrict__ ef = (unsigned int*)(ws + 4096);
    const int lane = threadIdx.x & 63;
    const int wave = threadIdx.x >> 6;
    const int row = blockIdx.x * 4 + wave;
    if (row >= nrows) return;
    const float* r = emb + (size_t)row * D;
    float4 v1 = *(const float4*)&r[lane * 4];
    float4 v2 = *(const float4*)&r[256 + lane * 4];
    float s = v1.x * v1.x + v1.y * v1.y + v1.z * v1.z + v1.w * v1.w
            + v2.x * v2.x + v2.y * v2.y + v2.z * v2.z + v2.w * v2.w;
    #pragma unroll
    for (int off = 32; off > 0; off >>= 1) s += __shfl_down(s, off, 64);
    const float rn = __shfl(rsqrtf(s), 0, 64);

    unsigned int p0 = __builtin_amdgcn_cvt_pk_fp8_f32(v1.x * rn, v1.y * rn, 0, false);
    p0 = __builtin_amdgcn_cvt_pk_fp8_f32(v1.z * rn, v1.w * rn, p0, true);
    unsigned int p1 = __builtin_amdgcn_cvt_pk_fp8_f32(v2.x * rn, v2.y * rn, 0, false);
    p1 = __builtin_amdgcn_cvt_pk_fp8_f32(v2.z * rn, v2.w * rn, p1, true);
    ef[(size_t)row * 128 + lane] = p0;        // bytes [lane*4, +4)
    ef[(size_t)row * 128 + 64 + lane] = p1;   // bytes [256 + lane*4, +4)
}

// Wave-per-tile, ZERO-LDS GEMM. 2080 upper-tri 64x64 tiles, one wave each
// (520 blocks x 4 waves). Key insight: S = E*E^T means both MFMA operands
// are contiguous row-slices — lane l's f8f6f4 fragment is bytes
// [kk*64 + (l>>5)*32, +32) of row (l&31) — so A and B load DIRECTLY from
// global into VGPRs. No LDS staging, no barriers, no glds drain, no round
// quantization (grid ~fully resident at ~8-12 waves/CU). Loads hidden by TLP.
__global__ __launch_bounds__(256, 2) void infonce_sim_kernel(
        const int* __restrict__ labels, float* __restrict__ ws) {
    // contiguous-per-XCD chunking (520 % 8 == 0)
    const int grp = gridDim.x >> 3;  // 65
    const int bs = (blockIdx.x & 7) * grp + (blockIdx.x >> 3);
    const int t = threadIdx.x;
    const int w = t >> 6, l = t & 63;
    const int tile = bs * 4 + w;
    // triangular decode: row-major over {(bi,bj): bj>=bi}
    int rem = tile, bi = 0;
    while (rem >= (NBT - bi)) { rem -= (NBT - bi); ++bi; }
    const int bj = bi + rem;

    const unsigned char* __restrict__ efp8 = (const unsigned char*)(ws + 4096);
    float* __restrict__ pvals = ws + 64;

    __shared__ int lab_row[4][64], lab_col[4][64];
    __shared__ float red[4];

    // per-wave label slices (same-wave write->read, no barrier needed)
    lab_row[w][l] = labels[(bi * 64 + l) >> 1];
    lab_col[w][l] = labels[(bj * 64 + l) >> 1];

    const int ln = l & 31;   // row within a 32-row quadrant panel
    const int hi = l >> 5;   // k-half selector within one MFMA's K=64

    // row base pointers; lane reads 32 B at +kk*64 (two uint4)
    const unsigned char* pa0 = efp8 + ((size_t)(bi * 64 + ln) << 9) + hi * 32;
    const unsigned char* pa1 = pa0 + ((size_t)32 << 9);  // ma=1: +32 rows
    const unsigned char* pb0 = efp8 + ((size_t)(bj * 64 + ln) << 9) + hi * 32;
    const unsigned char* pb1 = pb0 + ((size_t)32 << 9);

    f32x16 acc[4] = {};  // [ma*2+nb]

    #pragma unroll
    for (int kk = 0; kk < 8; ++kk) {
        const int ko = kk * 64;
        union { v8i v; uint4 q[2]; } a0, a1, b0, b1;
        a0.q[0] = *(const uint4*)(pa0 + ko);
        a0.q[1] = *(const uint4*)(pa0 + ko + 16);
        a1.q[0] = *(const uint4*)(pa1 + ko);
        a1.q[1] = *(const uint4*)(pa1 + ko + 16);
        b0.q[0] = *(const uint4*)(pb0 + ko);
        b0.q[1] = *(const uint4*)(pb0 + ko + 16);
        b1.q[0] = *(const uint4*)(pb1 + ko);
        b1.q[1] = *(const uint4*)(pb1 + ko + 16);
        acc[0] = __builtin_amdgcn_mfma_scale_f32_32x32x64_f8f6f4(
            a0.v, b0.v, acc[0], 0, 0, 0, 0x7F7F7F7F, 0, 0x7F7F7F7F);
        acc[1] = __builtin_amdgcn_mfma_scale_f32_32x32x64_f8f6f4(
            a0.v, b1.v, acc[1], 0, 0, 0, 0x7F7F7F7F, 0, 0x7F7F7F7F);
        acc[2] = __builtin_amdgcn_mfma_scale_f32_32x32x64_f8f6f4(
            a1.v, b0.v, acc[2], 0, 0, 0, 0x7F7F7F7F, 0, 0x7F7F7F7F);
        acc[3] = __builtin_amdgcn_mfma_scale_f32_32x32x64_f8f6f4(
            a1.v, b1.v, acc[3], 0, 0, 0, 0x7F7F7F7F, 0, 0x7F7F7F7F);
    }

    // Epilogue: 32x32 C/D layout: col = lane&31, row = (reg&3)+8*(reg>>2)+4*(lane>>5).
    const int rowA0 = bi * 64, rowB0 = bj * 64;
    float neg_local = 0.0f;
    #pragma unroll
    for (int ma = 0; ma < 2; ++ma) {
        #pragma unroll
        for (int nb = 0; nb < 2; ++nb) {
            const f32x16 a = acc[ma * 2 + nb];
            #pragma unroll
            for (int reg = 0; reg < 16; ++reg) {
                const int rrow = (reg & 3) + 8 * (reg >> 2) + 4 * hi;
                const int li = ma * 32 + rrow;
                const int lj = nb * 32 + ln;
                const int i = rowA0 + li;
                const int j = rowB0 + lj;
                const float S = a[reg] * TEMP_INV;
                if (j > i) {
                    if (lab_row[w][li] != lab_col[w][lj]) neg_local += __expf(S);
                    if (!(i & 1) && j == i + 1) pvals[i >> 1] = S;
                }
            }
        }
    }

    float s = neg_local;
    #pragma unroll
    for (int off = 32; off > 0; off >>= 1) s += __shfl_down(s, off, 64);
    if (l == 0) red[w] = s;
    __syncthreads();
    if (t == 0) atomicAdd(ws, red[0] + red[1] + red[2] + red[3]);
}

__global__ void infonce_loss_kernel(const float* __restrict__ ws,
                                    float* __restrict__ out, int npairs) {
    __shared__ float red[4];
    const float neg = ws[0];
    const float* __restrict__ p = ws + 64;
    float local = 0.0f;
    for (int k = threadIdx.x; k < npairs; k += 256) {
        const float pv = p[k];
        local += logf(__expf(pv) + neg) - pv;
    }
    float s = local;
    #pragma unroll
    for (int off = 32; off > 0; off >>= 1) s += __shfl_down(s, off, 64);
    if ((threadIdx.x & 63) == 0) red[threadIdx.x >> 6] = s;
    __syncthreads();
    if (threadIdx.x == 0)
        out[0] = (red[0] + red[1] + red[2] + red[3]) / (float)npairs;
}

extern "C" void kernel_launch(void* const* d_in, const int* in_sizes, int n_in,
                              void* d_out, int out_size, void* d_ws, size_t ws_size,
                              hipStream_t stream) {
    const float* emb = (const float*)d_in[0];
    const int* labels = (const int*)d_in[1];
    float* out = (float*)d_out;
    float* ws = (float*)d_ws;

    const int ntot = in_sizes[0] / D;  // 4096
    const int npairs = ntot / 2;       // 2048 positive pairs

    infonce_norm_cast_kernel<<<ntot / 4, 256, 0, stream>>>(emb, ws, ntot);
    infonce_sim_kernel<<<NBLKS, 256, 0, stream>>>(labels, ws);
    infonce_loss_kernel<<<1, 256, 0, stream>>>(ws, out, npairs);
}

// Round 13
// 85.541 us; speedup vs baseline: 1.2199x; 1.2199x over previous
//
#include <hip/hip_runtime.h>
#include <math.h>

#define D 512
#define TEMP_INV 14.285714285714286f  // 1/0.07
#define NBT 32                         // 4096 / 128 tile grid dim
#define NBLK (NBT * (NBT + 1) / 2)     // 528 upper-tri tiles

typedef int v8i __attribute__((ext_vector_type(8)));
typedef float f32x16 __attribute__((ext_vector_type(16)));

// global->LDS direct DMA, 16 B per lane. LDS dest = wave-uniform base + lane*16.
#define GLDS16(g, l) __builtin_amdgcn_global_load_lds(                         \
    (const __attribute__((address_space(1))) unsigned int*)(g),                \
    (__attribute__((address_space(3))) unsigned int*)(l), 16, 0, 0)

// ws layout (float units):
//   [0]                neg_sum accumulator (float atomic)
//   [64 .. 2112)       p values (positive-pair logits)
//   [2560 .. 18944)    scales: e8m0 byte per (row, 32-block) [4096][16] (64 KB)
//   [20480 .. 86016)   efp4: normalized fp4(e2m1) matrix [4096][256 B] (1 MB)

// fp4 e2m1 code for |x| (grid 0,.5,1,1.5,2,3,4,6), RNE-ish thresholds.
__device__ __forceinline__ unsigned fp4_code(float x) {
    const unsigned sg = (__float_as_uint(x) >> 31) << 3;
    const float u = fabsf(x);
    unsigned c = u < 0.25f ? 0u : u < 0.75f ? 1u : u < 1.25f ? 2u :
                 u < 1.75f ? 3u : u < 2.5f  ? 4u : u < 3.5f  ? 5u :
                 u < 5.0f  ? 6u : 7u;
    return c | sg;
}

// One wave per row: rsqrt(sum sq), per-32-block max -> e8m0 scale, fp4 encode.
__global__ void infonce_norm_cast_kernel(const float* __restrict__ emb,
                                         float* __restrict__ ws, int nrows) {
    if (blockIdx.x == 0 && threadIdx.x == 0) ws[0] = 0.0f;  // zero neg_sum
    unsigned char* __restrict__ scales = (unsigned char*)(ws + 2560);
    unsigned char* __restrict__ efp4 = (unsigned char*)(ws + 20480);
    const int lane = threadIdx.x & 63;
    const int wave = threadIdx.x >> 6;
    const int row = blockIdx.x * 4 + wave;
    if (row >= nrows) return;
    const float* r = emb + (size_t)row * D;
    float4 v1 = *(const float4*)&r[lane * 4];          // elems lane*4..+3
    float4 v2 = *(const float4*)&r[256 + lane * 4];    // elems 256+lane*4..+3
    float s = v1.x * v1.x + v1.y * v1.y + v1.z * v1.z + v1.w * v1.w
            + v2.x * v2.x + v2.y * v2.y + v2.z * v2.z + v2.w * v2.w;
    #pragma unroll
    for (int off = 32; off > 0; off >>= 1) s += __shfl_down(s, off, 64);
    const float rn = __shfl(rsqrtf(s), 0, 64);

    float f1[4] = {v1.x * rn, v1.y * rn, v1.z * rn, v1.w * rn};
    float f2[4] = {v2.x * rn, v2.y * rn, v2.z * rn, v2.w * rn};
    float m1 = fmaxf(fmaxf(fabsf(f1[0]), fabsf(f1[1])),
                     fmaxf(fabsf(f1[2]), fabsf(f1[3])));
    float m2 = fmaxf(fmaxf(fabsf(f2[0]), fabsf(f2[1])),
                     fmaxf(fabsf(f2[2]), fabsf(f2[3])));
    // 32-block = 8 consecutive lanes' quads; block1 = lane>>3, block2 = 8+that
    #pragma unroll
    for (int o = 1; o < 8; o <<= 1) {
        m1 = fmaxf(m1, __shfl_xor(m1, o, 64));
        m2 = fmaxf(m2, __shfl_xor(m2, o, 64));
    }
    int e1, e2;
    (void)frexpf(m1, &e1);  // m1 = f*2^e1, f in [0.5,1)
    (void)frexpf(m2, &e2);
    const int s1 = e1 - 2, s2 = e2 - 2;  // scaled max in [2,4) <= 6
    const float inv1 = ldexpf(1.0f, -s1), inv2 = ldexpf(1.0f, -s2);

    unsigned h1 = 0, h2 = 0;
    #pragma unroll
    for (int j = 0; j < 4; ++j) {
        h1 |= fp4_code(f1[j] * inv1) << (4 * j);
        h2 |= fp4_code(f2[j] * inv2) << (4 * j);
    }
    unsigned short* rp = (unsigned short*)(efp4 + (size_t)row * 256);
    rp[lane] = (unsigned short)h1;        // bytes [lane*2, +2)
    rp[64 + lane] = (unsigned short)h2;   // bytes [128 + lane*2, +2)
    if ((lane & 7) == 0) {
        scales[(size_t)row * 16 + (lane >> 3)] = (unsigned char)(127 + s1);
        scales[(size_t)row * 16 + 8 + (lane >> 3)] = (unsigned char)(127 + s2);
    }
}

// Upper-triangular 128x128 tiles (528 blocks, 2 blocks/CU: A+B = 64 KB LDS).
// fp4: full panels (128 x 256 B = 32 KB each), single-shot staging (16 glds
// per wave, ONE vmcnt drain at ONE barrier), 32 mfma_scale per wave with
// per-32-block e8m0 scales (fmt=4). Traffic ~36 MB vs R10's 68 MB — attacks
// the L3 poison-eviction contention floor. XOR swizzle: 16 B chunk c of row
// r at physical slot c ^ (r&7): glds coalesced, fragment = one b128 read.
__global__ __launch_bounds__(256, 2) void infonce_sim_kernel(
        const int* __restrict__ labels, float* __restrict__ ws) {
    // contiguous-per-XCD chunking (528 % 8 == 0)
    const int grp = gridDim.x >> 3;
    const int tile = (blockIdx.x & 7) * grp + (blockIdx.x >> 3);
    // triangular decode: row-major over {(bi,bj): bj>=bi}
    int rem = tile, bi = 0;
    while (rem >= (NBT - bi)) { rem -= (NBT - bi); ++bi; }
    const int bj = bi + rem;

    const unsigned char* __restrict__ scales = (const unsigned char*)(ws + 2560);
    const unsigned char* __restrict__ efp4 = (const unsigned char*)(ws + 20480);
    float* __restrict__ pvals = ws + 64;

    __shared__ __align__(16) unsigned char As[128 * 256];  // 32 KB
    __shared__ __align__(16) unsigned char Bs[128 * 256];  // 32 KB
    __shared__ int lab_row[128], lab_col[128];
    __shared__ float red[4];

    const int t = threadIdx.x;
    const int w = t >> 6, l = t & 63;
    const int wy = w >> 1, wx = w & 1;
    const int ln = l & 31;   // row/col within a 32x32 sub-tile
    const int hi = l >> 5;   // k-half selector within one MFMA's K=64
    const int rowA0 = bi * 128, rowB0 = bj * 128;

    if (t < 128) lab_row[t] = labels[(rowA0 + t) >> 1];
    else lab_col[t - 128] = labels[(rowB0 + t - 128) >> 1];

    // ---- single-shot staging: wave w stages rows [w*32, w*32+32) of A and B.
    // glds s covers 4 rows (64 lanes x 16 B; row = 256 B = 16 lanes). Lane l:
    // r = w*32 + s*4 + (l>>4), slot cl = l&15, global chunk c = cl ^ (r&7).
    {
        const int rgrp = l >> 4, cl = l & 15;
        #pragma unroll
        for (int s = 0; s < 8; ++s) {
            const int r = w * 32 + s * 4 + rgrp;
            const int c = cl ^ (r & 7);
            const size_t gofs = ((size_t)r << 8) + (c << 4);
            const int lbase = (w * 32 + s * 4) * 256;  // wave-uniform
            GLDS16(efp4 + (((size_t)rowA0) << 8) + gofs, &As[lbase]);
            GLDS16(efp4 + (((size_t)rowB0) << 8) + gofs, &Bs[lbase]);
        }
    }

    // per-lane scale dwords for the 4 rows this lane contributes, pre-shifted
    // by hi*8 so per-kk extraction is compile-time shifts only.
    const int ra0 = wy * 64 + ln, ra1 = ra0 + 32;
    const int rb0 = wx * 64 + ln, rb1 = rb0 + 32;
    uint4 sA0 = *(const uint4*)(scales + (size_t)(rowA0 + ra0) * 16);
    uint4 sA1 = *(const uint4*)(scales + (size_t)(rowA0 + ra1) * 16);
    uint4 sB0 = *(const uint4*)(scales + (size_t)(rowB0 + rb0) * 16);
    uint4 sB1 = *(const uint4*)(scales + (size_t)(rowB0 + rb1) * 16);
    const int sh = hi * 8;
    unsigned dA0[4] = {sA0.x >> sh, sA0.y >> sh, sA0.z >> sh, sA0.w >> sh};
    unsigned dA1[4] = {sA1.x >> sh, sA1.y >> sh, sA1.z >> sh, sA1.w >> sh};
    unsigned dB0[4] = {sB0.x >> sh, sB0.y >> sh, sB0.z >> sh, sB0.w >> sh};
    unsigned dB1[4] = {sB1.x >> sh, sB1.y >> sh, sB1.z >> sh, sB1.w >> sh};

    f32x16 acc[4] = {};  // [ma*2+nb]

    __syncthreads();  // single vmcnt(0) drain: 16 glds/wave in flight

    #pragma unroll
    for (int kk = 0; kk < 8; ++kk) {
        const int q = kk * 2 + hi;          // logical 16 B chunk = 32-block id
        const int p = (q ^ (ln & 7)) << 4;  // physical byte offset in row
        union { v8i v; uint4 u[2]; } a0, a1, b0, b1;
        a0.u[0] = *(const uint4*)&As[ra0 * 256 + p];
        a1.u[0] = *(const uint4*)&As[ra1 * 256 + p];
        b0.u[0] = *(const uint4*)&Bs[rb0 * 256 + p];
        b1.u[0] = *(const uint4*)&Bs[rb1 * 256 + p];
        a0.u[1] = a1.u[1] = b0.u[1] = b1.u[1] = make_uint4(0, 0, 0, 0);
        const int ks = 16 * (kk & 1), kd = kk >> 1;
        const int scA0 = (dA0[kd] >> ks) & 0xFF;
        const int scA1 = (dA1[kd] >> ks) & 0xFF;
        const int scB0 = (dB0[kd] >> ks) & 0xFF;
        const int scB1 = (dB1[kd] >> ks) & 0xFF;
        acc[0] = __builtin_amdgcn_mfma_scale_f32_32x32x64_f8f6f4(
            a0.v, b0.v, acc[0], 4, 4, 0, scA0, 0, scB0);  // fmt 4 = fp4
        acc[1] = __builtin_amdgcn_mfma_scale_f32_32x32x64_f8f6f4(
            a0.v, b1.v, acc[1], 4, 4, 0, scA0, 0, scB1);
        acc[2] = __builtin_amdgcn_mfma_scale_f32_32x32x64_f8f6f4(
            a1.v, b0.v, acc[2], 4, 4, 0, scA1, 0, scB0);
        acc[3] = __builtin_amdgcn_mfma_scale_f32_32x32x64_f8f6f4(
            a1.v, b1.v, acc[3], 4, 4, 0, scA1, 0, scB1);
    }

    // Epilogue: 32x32 C/D layout: col = lane&31, row = (reg&3)+8*(reg>>2)+4*(lane>>5).
    float neg_local = 0.0f;
    #pragma unroll
    for (int ma = 0; ma < 2; ++ma) {
        #pragma unroll
        for (int nb = 0; nb < 2; ++nb) {
            const f32x16 a = acc[ma * 2 + nb];
            #pragma unroll
            for (int reg = 0; reg < 16; ++reg) {
                const int rrow = (reg & 3) + 8 * (reg >> 2) + 4 * hi;
                const int li = wy * 64 + ma * 32 + rrow;
                const int lj = wx * 64 + nb * 32 + ln;
                const int i = rowA0 + li;
                const int j = rowB0 + lj;
                const float S = a[reg] * TEMP_INV;
                if (j > i) {
                    if (lab_row[li] != lab_col[lj]) neg_local += __expf(S);
                    if (!(i & 1) && j == i + 1) pvals[i >> 1] = S;
                }
            }
        }
    }

    float s = neg_local;
    #pragma unroll
    for (int off = 32; off > 0; off >>= 1) s += __shfl_down(s, off, 64);
    if (l == 0) red[w] = s;
    __syncthreads();
    if (t == 0) atomicAdd(ws, red[0] + red[1] + red[2] + red[3]);
}

__global__ void infonce_loss_kernel(const float* __restrict__ ws,
                                    float* __restrict__ out, int npairs) {
    __shared__ float red[4];
    const float neg = ws[0];
    const float* __restrict__ p = ws + 64;
    float local = 0.0f;
    for (int k = threadIdx.x; k < npairs; k += 256) {
        const float pv = p[k];
        local += logf(__expf(pv) + neg) - pv;
    }
    float s = local;
    #pragma unroll
    for (int off = 32; off > 0; off >>= 1) s += __shfl_down(s, off, 64);
    if ((threadIdx.x & 63) == 0) red[threadIdx.x >> 6] = s;
    __syncthreads();
    if (threadIdx.x == 0)
        out[0] = (red[0] + red[1] + red[2] + red[3]) / (float)npairs;
}

extern "C" void kernel_launch(void* const* d_in, const int* in_sizes, int n_in,
                              void* d_out, int out_size, void* d_ws, size_t ws_size,
                              hipStream_t stream) {
    const float* emb = (const float*)d_in[0];
    const int* labels = (const int*)d_in[1];
    float* out = (float*)d_out;
    float* ws = (float*)d_ws;

    const int ntot = in_sizes[0] / D;  // 4096
    const int npairs = ntot / 2;       // 2048 positive pairs

    infonce_norm_cast_kernel<<<ntot / 4, 256, 0, stream>>>(emb, ws, ntot);
    infonce_sim_kernel<<<NBLK, 256, 0, stream>>>(labels, ws);
    infonce_loss_kernel<<<1, 256, 0, stream>>>(ws, out, npairs);
}

// Round 14
// 84.971 us; speedup vs baseline: 1.2281x; 1.0067x over previous
//
#include <hip/hip_runtime.h>
#include <math.h>

#define D 512
#define TEMP_INV 14.285714285714286f  // 1/0.07
#define NBT 16                         // 4096 / 256 tile grid dim
#define NBLK (NBT * (NBT + 1) / 2)     // 136 upper-tri tiles

typedef int v8i __attribute__((ext_vector_type(8)));
typedef float f32x16 __attribute__((ext_vector_type(16)));

// global->LDS direct DMA, 16 B per lane. LDS dest = wave-uniform base + lane*16.
#define GLDS16(g, l) __builtin_amdgcn_global_load_lds(                         \
    (const __attribute__((address_space(1))) unsigned int*)(g),                \
    (__attribute__((address_space(3))) unsigned int*)(l), 16, 0, 0)

// ws layout (float units):
//   [0]                neg_sum accumulator (float atomic)
//   [64 .. 2112)       p values (positive-pair logits)
//   [2560 .. 18944)    scales: e8m0 byte per (row, 32-block) [4096][16] (64 KB)
//   [20480 .. 86016)   efp4: normalized fp4(e2m1) matrix [4096][256 B] (1 MB)

// fp4 e2m1 code for |x| (grid 0,.5,1,1.5,2,3,4,6), RNE-ish thresholds.
__device__ __forceinline__ unsigned fp4_code(float x) {
    const unsigned sg = (__float_as_uint(x) >> 31) << 3;
    const float u = fabsf(x);
    unsigned c = u < 0.25f ? 0u : u < 0.75f ? 1u : u < 1.25f ? 2u :
                 u < 1.75f ? 3u : u < 2.5f  ? 4u : u < 3.5f  ? 5u :
                 u < 5.0f  ? 6u : 7u;
    return c | sg;
}

// One wave per row: rsqrt(sum sq), per-32-block max -> e8m0 scale, fp4 encode.
__global__ void infonce_norm_cast_kernel(const float* __restrict__ emb,
                                         float* __restrict__ ws, int nrows) {
    if (blockIdx.x == 0 && threadIdx.x == 0) ws[0] = 0.0f;  // zero neg_sum
    unsigned char* __restrict__ scales = (unsigned char*)(ws + 2560);
    unsigned char* __restrict__ efp4 = (unsigned char*)(ws + 20480);
    const int lane = threadIdx.x & 63;
    const int wave = threadIdx.x >> 6;
    const int row = blockIdx.x * 4 + wave;
    if (row >= nrows) return;
    const float* r = emb + (size_t)row * D;
    float4 v1 = *(const float4*)&r[lane * 4];          // elems lane*4..+3
    float4 v2 = *(const float4*)&r[256 + lane * 4];    // elems 256+lane*4..+3
    float s = v1.x * v1.x + v1.y * v1.y + v1.z * v1.z + v1.w * v1.w
            + v2.x * v2.x + v2.y * v2.y + v2.z * v2.z + v2.w * v2.w;
    #pragma unroll
    for (int off = 32; off > 0; off >>= 1) s += __shfl_down(s, off, 64);
    const float rn = __shfl(rsqrtf(s), 0, 64);

    float f1[4] = {v1.x * rn, v1.y * rn, v1.z * rn, v1.w * rn};
    float f2[4] = {v2.x * rn, v2.y * rn, v2.z * rn, v2.w * rn};
    float m1 = fmaxf(fmaxf(fabsf(f1[0]), fabsf(f1[1])),
                     fmaxf(fabsf(f1[2]), fabsf(f1[3])));
    float m2 = fmaxf(fmaxf(fabsf(f2[0]), fabsf(f2[1])),
                     fmaxf(fabsf(f2[2]), fabsf(f2[3])));
    // 32-block = 8 consecutive lanes' quads; block1 = lane>>3, block2 = 8+that
    #pragma unroll
    for (int o = 1; o < 8; o <<= 1) {
        m1 = fmaxf(m1, __shfl_xor(m1, o, 64));
        m2 = fmaxf(m2, __shfl_xor(m2, o, 64));
    }
    int e1, e2;
    (void)frexpf(m1, &e1);  // m1 = f*2^e1, f in [0.5,1)
    (void)frexpf(m2, &e2);
    const int s1 = e1 - 2, s2 = e2 - 2;  // scaled max in [2,4) <= 6
    const float inv1 = ldexpf(1.0f, -s1), inv2 = ldexpf(1.0f, -s2);

    unsigned h1 = 0, h2 = 0;
    #pragma unroll
    for (int j = 0; j < 4; ++j) {
        h1 |= fp4_code(f1[j] * inv1) << (4 * j);
        h2 |= fp4_code(f2[j] * inv2) << (4 * j);
    }
    unsigned short* rp = (unsigned short*)(efp4 + (size_t)row * 256);
    rp[lane] = (unsigned short)h1;        // bytes [lane*2, +2)
    rp[64 + lane] = (unsigned short)h2;   // bytes [128 + lane*2, +2)
    if ((lane & 7) == 0) {
        scales[(size_t)row * 16 + (lane >> 3)] = (unsigned char)(127 + s1);
        scales[(size_t)row * 16 + 8 + (lane >> 3)] = (unsigned char)(127 + s2);
    }
}

// Upper-triangular 256x256 tiles (136 blocks, 1/CU: A+B = 128 KB LDS), 512
// threads (8 waves). fp4 panels (256 x 256 B = 64 KB each), single-shot
// staging (16 glds/wave, ONE vmcnt drain at ONE barrier). Wave w -> 64x128
// output slab (wr=w>>1, wc=w&1): 2x4 acc tiles of 32x32, 64 mfma_scale with
// per-32-block e8m0 scales (fmt=4). Traffic ~18 MB vs R13's 35 MB — the
// last halving of the L3-drain-contention term. Same XOR swizzle: 16 B
// chunk c of row r at slot c ^ (r&7).
__global__ __launch_bounds__(512, 1) void infonce_sim_kernel(
        const int* __restrict__ labels, float* __restrict__ ws) {
    // contiguous-per-XCD chunking (136 % 8 == 0)
    const int grp = gridDim.x >> 3;  // 17
    const int tile = (blockIdx.x & 7) * grp + (blockIdx.x >> 3);
    // triangular decode: row-major over {(bi,bj): bj>=bi}
    int rem = tile, bi = 0;
    while (rem >= (NBT - bi)) { rem -= (NBT - bi); ++bi; }
    const int bj = bi + rem;

    const unsigned char* __restrict__ scales = (const unsigned char*)(ws + 2560);
    const unsigned char* __restrict__ efp4 = (const unsigned char*)(ws + 20480);
    float* __restrict__ pvals = ws + 64;

    __shared__ __align__(16) unsigned char As[256 * 256];  // 64 KB
    __shared__ __align__(16) unsigned char Bs[256 * 256];  // 64 KB
    __shared__ int lab_row[256], lab_col[256];
    __shared__ float red[8];

    const int t = threadIdx.x;
    const int w = t >> 6, l = t & 63;
    const int wr = w >> 1, wc = w & 1;   // 4x2 wave grid over 256x256 out
    const int ln = l & 31;   // row/col within a 32x32 sub-tile
    const int hi = l >> 5;   // k-half selector within one MFMA's K=64
    const int rowA0 = bi * 256, rowB0 = bj * 256;

    if (t < 256) lab_row[t] = labels[(rowA0 + t) >> 1];
    else lab_col[t - 256] = labels[(rowB0 + t - 256) >> 1];

    // ---- single-shot staging: wave w stages rows [w*32, w*32+32) of A and B.
    // glds s covers 4 rows (64 lanes x 16 B; row = 256 B = 16 lanes). Lane l:
    // r = w*32 + s*4 + (l>>4), slot cl = l&15, global chunk c = cl ^ (r&7).
    {
        const int rgrp = l >> 4, cl = l & 15;
        #pragma unroll
        for (int s = 0; s < 8; ++s) {
            const int r = w * 32 + s * 4 + rgrp;
            const int c = cl ^ (r & 7);
            const size_t gofs = ((size_t)r << 8) + (c << 4);
            const int lbase = (w * 32 + s * 4) * 256;  // wave-uniform
            GLDS16(efp4 + (((size_t)rowA0) << 8) + gofs, &As[lbase]);
            GLDS16(efp4 + (((size_t)rowB0) << 8) + gofs, &Bs[lbase]);
        }
    }

    // per-lane scale dwords, pre-shifted by hi*8 -> per-kk compile-time shifts.
    const int ra0 = wr * 64 + ln, ra1 = ra0 + 32;
    const int sh = hi * 8;
    unsigned dA[2][4], dB[4][4];
    {
        uint4 sa0 = *(const uint4*)(scales + (size_t)(rowA0 + ra0) * 16);
        uint4 sa1 = *(const uint4*)(scales + (size_t)(rowA0 + ra1) * 16);
        dA[0][0] = sa0.x >> sh; dA[0][1] = sa0.y >> sh;
        dA[0][2] = sa0.z >> sh; dA[0][3] = sa0.w >> sh;
        dA[1][0] = sa1.x >> sh; dA[1][1] = sa1.y >> sh;
        dA[1][2] = sa1.z >> sh; dA[1][3] = sa1.w >> sh;
        #pragma unroll
        for (int nb = 0; nb < 4; ++nb) {
            const int rb = wc * 128 + nb * 32 + ln;
            uint4 sb = *(const uint4*)(scales + (size_t)(rowB0 + rb) * 16);
            dB[nb][0] = sb.x >> sh; dB[nb][1] = sb.y >> sh;
            dB[nb][2] = sb.z >> sh; dB[nb][3] = sb.w >> sh;
        }
    }

    f32x16 acc[2][4] = {};

    __syncthreads();  // single vmcnt(0) drain: 16 glds/wave in flight

    #pragma unroll
    for (int kk = 0; kk < 8; ++kk) {
        const int q = kk * 2 + hi;          // logical 16 B chunk = 32-block id
        const int p = (q ^ (ln & 7)) << 4;  // physical byte offset in row
        const int ks = 16 * (kk & 1), kd = kk >> 1;
        union { v8i v; uint4 u[2]; } a[2], b[4];
        #pragma unroll
        for (int ma = 0; ma < 2; ++ma) {
            a[ma].u[0] = *(const uint4*)&As[(wr * 64 + ma * 32 + ln) * 256 + p];
            a[ma].u[1] = make_uint4(0, 0, 0, 0);
        }
        #pragma unroll
        for (int nb = 0; nb < 4; ++nb) {
            b[nb].u[0] = *(const uint4*)&Bs[(wc * 128 + nb * 32 + ln) * 256 + p];
            b[nb].u[1] = make_uint4(0, 0, 0, 0);
        }
        #pragma unroll
        for (int ma = 0; ma < 2; ++ma) {
            const int scA = (dA[ma][kd] >> ks) & 0xFF;
            #pragma unroll
            for (int nb = 0; nb < 4; ++nb) {
                const int scB = (dB[nb][kd] >> ks) & 0xFF;
                acc[ma][nb] = __builtin_amdgcn_mfma_scale_f32_32x32x64_f8f6f4(
                    a[ma].v, b[nb].v, acc[ma][nb], 4, 4, 0, scA, 0, scB);
            }
        }
    }

    // Epilogue: 32x32 C/D layout: col = lane&31, row = (reg&3)+8*(reg>>2)+4*(lane>>5).
    float neg_local = 0.0f;
    #pragma unroll
    for (int ma = 0; ma < 2; ++ma) {
        #pragma unroll
        for (int nb = 0; nb < 4; ++nb) {
            const f32x16 a = acc[ma][nb];
            #pragma unroll
            for (int reg = 0; reg < 16; ++reg) {
                const int rrow = (reg & 3) + 8 * (reg >> 2) + 4 * hi;
                const int li = wr * 64 + ma * 32 + rrow;
                const int lj = wc * 128 + nb * 32 + ln;
                const int i = rowA0 + li;
                const int j = rowB0 + lj;
                const float S = a[reg] * TEMP_INV;
                if (j > i) {
                    if (lab_row[li] != lab_col[lj]) neg_local += __expf(S);
                    if (!(i & 1) && j == i + 1) pvals[i >> 1] = S;
                }
            }
        }
    }

    float s = neg_local;
    #pragma unroll
    for (int off = 32; off > 0; off >>= 1) s += __shfl_down(s, off, 64);
    if (l == 0) red[w] = s;
    __syncthreads();
    if (t == 0) {
        float tot = 0.0f;
        #pragma unroll
        for (int q = 0; q < 8; ++q) tot += red[q];
        atomicAdd(ws, tot);
    }
}

__global__ void infonce_loss_kernel(const float* __restrict__ ws,
                                    float* __restrict__ out, int npairs) {
    __shared__ float red[4];
    const float neg = ws[0];
    const float* __restrict__ p = ws + 64;
    float local = 0.0f;
    for (int k = threadIdx.x; k < npairs; k += 256) {
        const float pv = p[k];
        local += logf(__expf(pv) + neg) - pv;
    }
    float s = local;
    #pragma unroll
    for (int off = 32; off > 0; off >>= 1) s += __shfl_down(s, off, 64);
    if ((threadIdx.x & 63) == 0) red[threadIdx.x >> 6] = s;
    __syncthreads();
    if (threadIdx.x == 0)
        out[0] = (red[0] + red[1] + red[2] + red[3]) / (float)npairs;
}

extern "C" void kernel_launch(void* const* d_in, const int* in_sizes, int n_in,
                              void* d_out, int out_size, void* d_ws, size_t ws_size,
                              hipStream_t stream) {
    const float* emb = (const float*)d_in[0];
    const int* labels = (const int*)d_in[1];
    float* out = (float*)d_out;
    float* ws = (float*)d_ws;

    const int ntot = in_sizes[0] / D;  // 4096
    const int npairs = ntot / 2;       // 2048 positive pairs

    infonce_norm_cast_kernel<<<ntot / 4, 256, 0, stream>>>(emb, ws, ntot);
    infonce_sim_kernel<<<NBLK, 512, 0, stream>>>(labels, ws);
    infonce_loss_kernel<<<1, 256, 0, stream>>>(ws, out, npairs);
}